// Round 1
// baseline (267.783 us; speedup 1.0000x reference)
//
#include <hip/hip_runtime.h>

// Problem constants (from reference setup_inputs)
#define S_   8
#define N_   1024
#define KG_  16     // groups
#define MW_  64     // window length = N/K
#define CI_  128
#define CO_  256

// ---------------------------------------------------------------------------
// Kernel 1: circular sliding-window sums.
// win[s][t][c] = sum_{m=0}^{63} x[s][(t+m)%N][c]
// One block per (s, 64-t-tile): stage 128 rows in LDS, running-sum per thread.
// ---------------------------------------------------------------------------
__global__ __launch_bounds__(256) void win_kernel(const float* __restrict__ x,
                                                  float* __restrict__ win) {
    __shared__ float lds[128][CI_];          // 64 KB
    const int b   = blockIdx.x;              // 0..127
    const int s   = b >> 4;
    const int t0  = (b & 15) << 6;           // tile start
    const float* xs = x + (size_t)s * N_ * CI_;
    const int tid = threadIdx.x;

    // load rows t0 .. t0+127 (mod N), coalesced
    for (int e = tid; e < 128 * CI_; e += 256) {
        const int r = e >> 7;                // row within tile
        const int c = e & (CI_ - 1);
        lds[r][c] = xs[(((t0 + r) & (N_ - 1)) * CI_) + c];
    }
    __syncthreads();

    const int c     = tid & (CI_ - 1);
    const int tbase = (tid >> 7) * 32;       // 0 or 32: each thread does 32 t's
    float w = 0.f;
    #pragma unroll
    for (int m = 0; m < MW_; ++m) w += lds[tbase + m][c];

    float* wo = win + (size_t)s * N_ * CI_;
    wo[(t0 + tbase) * CI_ + c] = w;
    for (int t = 1; t < 32; ++t) {
        w += lds[tbase + t - 1 + MW_][c] - lds[tbase + t - 1][c];
        wo[(t0 + tbase + t) * CI_ + c] = w;
    }
}

// ---------------------------------------------------------------------------
// Kernel 2: out[s,n,o] = sum_{g,c} win[s,(n+g*64)%N,c] * W[g,o,c]
// Tiled fp32 GEMM: M=8192 (s,n), N=256 (o), K=2048 (g,c).
// Block tile 64x64, BK=32, 256 threads (16x16), 4x4 micro-tile per thread.
// A rows gathered circularly from win; B is W with c fastest (coalesced load,
// k-major LDS layout with padding for conflict-free staging).
// ---------------------------------------------------------------------------
#define BM 64
#define BN 64
#define BK 32
#define PAD 4

__global__ __launch_bounds__(256) void gemm_kernel(const float* __restrict__ win,
                                                   const float* __restrict__ W,
                                                   float* __restrict__ out) {
    __shared__ float As[BK][BM + PAD];       // k-major
    __shared__ float Bs[BK][BN + PAD];

    const int mb = blockIdx.x;               // 0..127  (s,n tile)
    const int nb = blockIdx.y;               // 0..3    (o tile)
    const int s  = mb >> 4;
    const int n0 = (mb & 15) << 6;
    const int o0 = nb << 6;

    const int tid = threadIdx.x;
    const int tx  = tid & 15;                // o micro
    const int ty  = tid >> 4;                // row micro

    float acc[4][4] = {};

    const float* wins = win + (size_t)s * N_ * CI_;
    const int j  = tid & 31;                 // k within BK for staging
    const int i0 = tid >> 5;                 // 0..7

    for (int g = 0; g < KG_; ++g) {
        const float* Wg = W + ((size_t)g * CO_ + o0) * CI_;
        for (int c0 = 0; c0 < CI_; c0 += BK) {
            // stage A: As[j][i] = win[s][(n0+i+g*64)%N][c0+j]
            #pragma unroll
            for (int i = i0; i < BM; i += 8) {
                const int row = (n0 + i + g * MW_) & (N_ - 1);
                As[j][i] = wins[row * CI_ + c0 + j];
            }
            // stage B: Bs[j][o'] = W[g][o0+o'][c0+j]
            #pragma unroll
            for (int o = i0; o < BN; o += 8) {
                Bs[j][o] = Wg[o * CI_ + c0 + j];
            }
            __syncthreads();

            #pragma unroll
            for (int kk = 0; kk < BK; ++kk) {
                float a[4], bv[4];
                #pragma unroll
                for (int i = 0; i < 4; ++i) a[i] = As[kk][ty * 4 + i];
                #pragma unroll
                for (int jj = 0; jj < 4; ++jj) bv[jj] = Bs[kk][tx * 4 + jj];
                #pragma unroll
                for (int i = 0; i < 4; ++i)
                    #pragma unroll
                    for (int jj = 0; jj < 4; ++jj)
                        acc[i][jj] += a[i] * bv[jj];
            }
            __syncthreads();
        }
    }

    float* outp = out + ((size_t)s * N_ + n0) * CO_ + o0;
    #pragma unroll
    for (int i = 0; i < 4; ++i) {
        const int r = ty * 4 + i;
        #pragma unroll
        for (int jj = 0; jj < 4; ++jj)
            outp[r * CO_ + tx * 4 + jj] = acc[i][jj];
    }
}

extern "C" void kernel_launch(void* const* d_in, const int* in_sizes, int n_in,
                              void* d_out, int out_size, void* d_ws, size_t ws_size,
                              hipStream_t stream) {
    const float* x = (const float*)d_in[0];   // [S, N, CI]
    const float* W = (const float*)d_in[1];   // [K, CO, CI]
    // d_in[2] (splits) is implied by the circulant structure: (g*64+m+n)%N.

    float* win = (float*)d_ws;                // [S, N, CI] fp32 = 4 MB scratch
    float* out = (float*)d_out;               // [S, N, CO]

    win_kernel<<<128, 256, 0, stream>>>(x, win);

    dim3 grid(128, 4);
    gemm_kernel<<<grid, 256, 0, stream>>>(win, W, out);
}

// Round 2
// 95.289 us; speedup vs baseline: 2.8102x; 2.8102x over previous
//
#include <hip/hip_runtime.h>
#include <hip/hip_bf16.h>

#define S_   8
#define N_   1024
#define KG_  16
#define MW_  64
#define CI_  128
#define CO_  256

typedef __attribute__((ext_vector_type(8))) short bf16x8;
typedef __attribute__((ext_vector_type(4))) float f32x4;

// ---------------------------------------------------------------------------
// W fp32 -> bf16
// ---------------------------------------------------------------------------
__global__ __launch_bounds__(256) void wconv_kernel(const float* __restrict__ W,
                                                    __hip_bfloat16* __restrict__ Wb) {
    const int i = (blockIdx.x * 256 + threadIdx.x) * 4;
    const float4 v = *(const float4*)&W[i];
    Wb[i + 0] = __float2bfloat16(v.x);
    Wb[i + 1] = __float2bfloat16(v.y);
    Wb[i + 2] = __float2bfloat16(v.z);
    Wb[i + 3] = __float2bfloat16(v.w);
}

// ---------------------------------------------------------------------------
// win[s][t][c] = sum_{m<64} x[s][(t+m)%N][c], stored bf16.
// 256 blocks: (s, 32-t tile). LDS stages 96 rows; sliding-window update.
// ---------------------------------------------------------------------------
__global__ __launch_bounds__(256) void win_kernel(const float* __restrict__ x,
                                                  __hip_bfloat16* __restrict__ win) {
    __shared__ float lds[96][CI_];           // 48 KB
    const int b   = blockIdx.x;              // 0..255
    const int s   = b >> 5;
    const int t0  = (b & 31) << 5;           // 32 t's per block
    const float* xs = x + (size_t)s * N_ * CI_;
    const int tid = threadIdx.x;

    for (int e = tid * 4; e < 96 * CI_; e += 256 * 4) {
        const int r = e >> 7;
        const int c = e & (CI_ - 1);
        *(float4*)&lds[r][c] = *(const float4*)&xs[((t0 + r) & (N_ - 1)) * CI_ + c];
    }
    __syncthreads();

    const int c  = tid & (CI_ - 1);
    const int tb = (tid >> 7) << 4;          // 0 or 16: 16 t's per thread
    float s0 = 0.f, s1 = 0.f, s2 = 0.f, s3 = 0.f;
    #pragma unroll
    for (int m = 0; m < MW_; m += 4) {
        s0 += lds[tb + m + 0][c];
        s1 += lds[tb + m + 1][c];
        s2 += lds[tb + m + 2][c];
        s3 += lds[tb + m + 3][c];
    }
    float w = (s0 + s1) + (s2 + s3);
    __hip_bfloat16* wo = win + (size_t)s * N_ * CI_;
    wo[(t0 + tb) * CI_ + c] = __float2bfloat16(w);
    #pragma unroll
    for (int t = 1; t < 16; ++t) {
        w += lds[tb + t - 1 + MW_][c] - lds[tb + t - 1][c];
        wo[(t0 + tb + t) * CI_ + c] = __float2bfloat16(w);
    }
}

// ---------------------------------------------------------------------------
// out[s,n,o] = sum_{g,c} win[s,(n+64g)%N,c] * W[g,o,c]
// MFMA GEMM: M=8192 (s,n), N=256 (o), K=2048 (g,c).
// Block tile 128x64, grid (64,4) = 256 blocks (1/CU). 4 waves, wave = 64x32
// (4x2 frags of 16x16x32 bf16). BK=128 (one g per step), 16 K-steps.
// LDS double-buffered (96 KB). Staging: global_load_lds width 16 with
// pre-swizzled source (slot ^= row&7) -> 2-way-free ds_read_b128.
// Single barrier per step: stage(next) issued before compute(cur).
// ---------------------------------------------------------------------------
#define BKE  128
#define ASZ  (128 * BKE)   // 16384 elems, 32 KB
#define BSZ  (64  * BKE)   // 8192 elems, 16 KB

__global__ __launch_bounds__(256) void gemm_kernel(const __hip_bfloat16* __restrict__ winb,
                                                   const __hip_bfloat16* __restrict__ Wb,
                                                   float* __restrict__ out) {
    __shared__ __align__(16) unsigned short Alds[2 * ASZ];   // 64 KB
    __shared__ __align__(16) unsigned short Blds[2 * BSZ];   // 32 KB

    const int tid = threadIdx.x;
    const int l   = tid & 63;
    const int wv  = tid >> 6;
    const int mb  = blockIdx.x;              // 0..63
    const int s   = mb >> 3;
    const int n0  = (mb & 7) << 7;           // 128-row tile
    const int o0  = blockIdx.y << 6;         // 64-col tile

    const int wm = wv >> 1;                  // 0..1: row half (64 rows)
    const int wn = wv & 1;                   // 0..1: col half (32 cols)
    const int fr = l & 15;
    const int kq = l >> 4;

    const unsigned short* winp = (const unsigned short*)winb + (size_t)s * N_ * CI_;
    const unsigned short* Wp   = (const unsigned short*)Wb;

    const int rl = l >> 4;                   // staging: row within 4-row chunk
    const int ps = l & 15;                   // staging: physical 16B slot

    f32x4 acc[4][2];
    #pragma unroll
    for (int i = 0; i < 4; ++i)
        #pragma unroll
        for (int j = 0; j < 2; ++j)
            acc[i][j] = f32x4{0.f, 0.f, 0.f, 0.f};

    // All 4 waves stage: A = 32 chunks of 1KB (8/wave), B = 16 chunks (4/wave).
    auto stage = [&](int g, int buf) {
        unsigned short* Ab = &Alds[buf * ASZ];
        unsigned short* Bb = &Blds[buf * BSZ];
        #pragma unroll
        for (int q = 0; q < 8; ++q) {
            const int rb   = wv * 32 + q * 4;
            const int row  = rb + rl;
            const int ss   = ps ^ (row & 7);       // logical slot for this lane
            const int grow = (n0 + (g << 6) + row) & (N_ - 1);
            const unsigned short* src = winp + grow * CI_ + ss * 8;
            __builtin_amdgcn_global_load_lds((const __attribute__((address_space(1))) void*)src,
                                             (__attribute__((address_space(3))) void*)(Ab + rb * BKE),
                                             16, 0, 0);
        }
        #pragma unroll
        for (int q = 0; q < 4; ++q) {
            const int rb  = wv * 16 + q * 4;
            const int row = rb + rl;               // o index within tile
            const int ss  = ps ^ (row & 7);
            const unsigned short* src = Wp + ((g * CO_ + o0 + row) * CI_) + ss * 8;
            __builtin_amdgcn_global_load_lds((const __attribute__((address_space(1))) void*)src,
                                             (__attribute__((address_space(3))) void*)(Bb + rb * BKE),
                                             16, 0, 0);
        }
    };

    stage(0, 0);
    __syncthreads();

    for (int g = 0; g < KG_; ++g) {
        const int cur = g & 1;
        if (g + 1 < KG_) stage(g + 1, cur ^ 1);

        const unsigned short* Ab = &Alds[cur * ASZ];
        const unsigned short* Bb = &Blds[cur * BSZ];
        #pragma unroll
        for (int ksub = 0; ksub < 4; ++ksub) {
            const int sl = ksub * 4 + kq;          // logical 16B slot 0..15
            bf16x8 af[4], bfr[2];
            #pragma unroll
            for (int i = 0; i < 4; ++i) {
                const int row = wm * 64 + i * 16 + fr;
                af[i] = *(const bf16x8*)&Ab[row * BKE + ((sl ^ (row & 7)) * 8)];
            }
            #pragma unroll
            for (int j = 0; j < 2; ++j) {
                const int col = wn * 32 + j * 16 + fr;
                bfr[j] = *(const bf16x8*)&Bb[col * BKE + ((sl ^ (col & 7)) * 8)];
            }
            #pragma unroll
            for (int i = 0; i < 4; ++i)
                #pragma unroll
                for (int j = 0; j < 2; ++j)
                    acc[i][j] = __builtin_amdgcn_mfma_f32_16x16x32_bf16(af[i], bfr[j], acc[i][j], 0, 0, 0);
        }
        __syncthreads();   // drains vmcnt(0): next buffer staged; cur reads done
    }

    // D layout (m89): col = lane&15, row = (lane>>4)*4 + reg
    float* op = out + ((size_t)(s * N_ + n0 + wm * 64) * CO_) + o0 + wn * 32;
    #pragma unroll
    for (int i = 0; i < 4; ++i)
        #pragma unroll
        for (int j = 0; j < 2; ++j)
            #pragma unroll
            for (int r = 0; r < 4; ++r)
                op[(i * 16 + kq * 4 + r) * CO_ + j * 16 + fr] = acc[i][j][r];
}

extern "C" void kernel_launch(void* const* d_in, const int* in_sizes, int n_in,
                              void* d_out, int out_size, void* d_ws, size_t ws_size,
                              hipStream_t stream) {
    const float* x = (const float*)d_in[0];   // [S, N, CI]
    const float* W = (const float*)d_in[1];   // [K, CO, CI]

    __hip_bfloat16* winb = (__hip_bfloat16*)d_ws;                          // 2 MB
    __hip_bfloat16* Wbb  = (__hip_bfloat16*)((char*)d_ws +
                              (size_t)S_ * N_ * CI_ * sizeof(__hip_bfloat16)); // 1 MB
    float* out = (float*)d_out;               // [S, N, CO] fp32

    wconv_kernel<<<512, 256, 0, stream>>>(W, Wbb);
    win_kernel<<<256, 256, 0, stream>>>(x, winb);
    gemm_kernel<<<dim3(64, 4), 256, 0, stream>>>(winb, Wbb, out);
}